// Round 7
// baseline (248.493 us; speedup 1.0000x reference)
//
#include <hip/hip_runtime.h>

#define SEQ 2048
#define DHEAD 128
#define BK 32
#define NBH 32

typedef __attribute__((ext_vector_type(8))) short bf16x8;
typedef __attribute__((ext_vector_type(4))) short bf16x4;
typedef __attribute__((ext_vector_type(16))) float f32x16;
typedef __attribute__((ext_vector_type(4))) unsigned int u32x4;

__device__ __forceinline__ unsigned short f2bf(float f) {
    unsigned u = __builtin_bit_cast(unsigned, f);
    u += 0x7fffu + ((u >> 16) & 1u);
    return (unsigned short)(u >> 16);
}

__device__ __forceinline__ float fexp2(float x) {
    float r;
    asm("v_exp_f32 %0, %1" : "=v"(r) : "v"(x));   // native 2^x
    return r;
}

// Fused prepass -> FRAGMENT-MAJOR global layouts (no LDS anywhere).
// K: kout[bh][kt][s][hi][c5][8] bf16, element = K[l = kt*32+c5][d = s*16+hi*8+j].
//    Round-7: LDS transpose removed — each thread gathers its 8 d-elements
//    directly (per-load the wave reads 2x128B coalesced segments), packs with
//    v_cvt_pk_bf16_f32, stores one dwordx4.
// V: vout[bh][kt][u][a][hi][c5][8] bf16, element = V[dv = u*32+c5]
//    [kl = 16a + 8*(j>>2) + 4*hi + (j&3)]  (kl bit2<->3 permutation matching
//    the in-register P fragment order — verified rounds 1-6).
__global__ __launch_bounds__(256)
void cvt_kernel(const float* __restrict__ kin, const float* __restrict__ vin,
                unsigned short* __restrict__ kout, unsigned short* __restrict__ vout) {
    const int tid = threadIdx.x;
    if (blockIdx.x < 4096) {
        // K path: thread -> (bh, kt, s, hi, c5)
        int idx = blockIdx.x * 256 + tid;
        int c5 = idx & 31;
        int hi = (idx >> 5) & 1;
        int s  = (idx >> 6) & 7;
        int kt = (idx >> 9) & 63;
        int bh = idx >> 15;
        const float* ip = kin + ((size_t)bh * DHEAD + (s * 16 + hi * 8)) * SEQ + kt * 32 + c5;
        unsigned pw[4];
#pragma unroll
        for (int jj = 0; jj < 4; ++jj) {
            float f0 = ip[(size_t)(2 * jj) * SEQ];
            float f1 = ip[(size_t)(2 * jj + 1) * SEQ];
            unsigned r;
            asm("v_cvt_pk_bf16_f32 %0, %1, %2" : "=v"(r) : "v"(f0), "v"(f1));
            pw[jj] = r;
        }
        size_t off = ((size_t)bh * 64 + kt) * 4096 + (size_t)(((s * 2 + hi) * 32 + c5) * 8);
        *(u32x4*)&kout[off] = (u32x4){pw[0], pw[1], pw[2], pw[3]};
    } else {
        size_t f = ((size_t)(blockIdx.x - 4096) * 256 + tid) * 8;
        int bh  = (int)(f >> 18);
        int rem = (int)(f & 262143);
        int kt  = rem >> 12;
        int r2  = rem & 4095;
        int dv  = r2 >> 5;
        int e0  = r2 & 31;
        const float* src = vin + ((size_t)bh * DHEAD + dv) * SEQ + kt * BK + e0;
        float4 a = *(const float4*)src;
        float4 b = *(const float4*)(src + 4);
        unsigned short p0[4] = {f2bf(a.x), f2bf(a.y), f2bf(a.z), f2bf(a.w)};  // kl e0+0..3 (hi=0)
        unsigned short p1[4] = {f2bf(b.x), f2bf(b.y), f2bf(b.z), f2bf(b.w)};  // kl e0+4..7 (hi=1)
        // kl = 16*aa + 8*bb + 4*h + t  ->  frag coords a=aa, j = 4*bb + t, hi = h
        const int aa = e0 >> 4;
        const int bb = (e0 >> 3) & 1;
        const int u  = dv >> 5;
        const int cv = dv & 31;
        size_t tb = ((size_t)bh * 64 + kt) * 4096;
        size_t o0 = tb + (size_t)((((u * 2 + aa) * 2 + 0) * 32 + cv) * 8 + 4 * bb);
        size_t o1 = tb + (size_t)((((u * 2 + aa) * 2 + 1) * 32 + cv) * 8 + 4 * bb);
        *(bf16x4*)&vout[o0] = *(bf16x4*)p0;
        *(bf16x4*)&vout[o1] = *(bf16x4*)p1;
    }
}

// LDS-free attention with REGISTER DOUBLE-BUFFER PREFETCH (T14).
// Round-6 counters: MFMA 41us + VALU 35us + VMEM 41us ran ~serially (sum =
// 117 ~= 115 measured). This round issues tile kt+1's 12 fragment loads
// BEFORE computing tile kt, so the compiler's vmcnt wait lands before the
// NEXT iteration's MFMAs — the whole VMEM pipe hides under compute. Unroll
// x2 with named A/B frag sets keeps all indexing compile-time (rule #20).
// +48 VGPR (~156V + 64A = 220 unified) keeps 2 waves/SIMD.
__global__ __launch_bounds__(256, 2)
void attn_main(const float* __restrict__ q,
               const unsigned short* __restrict__ kF,
               const unsigned short* __restrict__ vF,
               const float* __restrict__ gamma,
               float* __restrict__ out) {
    const int tid  = threadIdx.x;
    const int wv   = tid >> 6;
    const int lane = tid & 63;
    const int c5   = lane & 31;
    const int hi   = lane >> 5;
    const int qh   = wv & 1;             // q 64-half
    const int dh   = wv >> 1;            // dv 64-half

    const int bh  = blockIdx.x & 31;     // same-head blocks stride 32 -> same XCD
    const int qlb = blockIdx.x >> 5;     // 0..15
    const size_t base = (size_t)bh * SEQ * DHEAD;   // == bh*64*4096

    const float* qp = q + base;              // fp32 [d][2048]
    const unsigned short* kb = kF + base;    // frag-major K
    const unsigned short* vb = vF + base;    // frag-major V
    float* op = out + base;                  // [dv][2048]

    const int ql0 = qlb * 128 + qh * 64;
    const float SCL = 0.08838834764831845f * 1.44269504088896340f; // 1/sqrt(128)*log2e

    // Q B-frags (one-time): B[n=ql][k=hi*8+j], d = s*16 + hi*8 + j
    bf16x8 qf0[8], qf1[8];
#pragma unroll
    for (int s = 0; s < 8; ++s) {
        bf16x8 t0, t1;
#pragma unroll
        for (int j = 0; j < 8; ++j) {
            const size_t drow = (size_t)(s * 16 + hi * 8 + j) * SEQ;
            t0[j] = (short)f2bf(qp[drow + ql0 + c5] * SCL);
            t1[j] = (short)f2bf(qp[drow + ql0 + 32 + c5] * SCL);
        }
        qf0[s] = t0;
        qf1[s] = t1;
    }

    f32x16 acc0[2], acc1[2];
#pragma unroll
    for (int t = 0; t < 2; ++t)
#pragma unroll
        for (int i = 0; i < 16; ++i) { acc0[t][i] = 0.f; acc1[t][i] = 0.f; }
    float lp0 = 0.f, lp1 = 0.f;

    const int ko = lane * 8;             // K frag: s*512 + lane*8
    int voff[4];                         // V frag (t2, a) for this dv-half
#pragma unroll
    for (int t2 = 0; t2 < 2; ++t2)
#pragma unroll
        for (int a = 0; a < 2; ++a)
            voff[t2 * 2 + a] = (((dh * 2 + t2) * 2 + a) * 2 + hi) * 256 + c5 * 8;

    bf16x8 kfA[8], vfA[4], kfB[8], vfB[4];

    auto load_tile = [&](int kt, bf16x8* kf, bf16x8* vf) {
        const unsigned short* kT = kb + (size_t)kt * 4096;
        const unsigned short* vT = vb + (size_t)kt * 4096;
#pragma unroll
        for (int s = 0; s < 8; ++s) kf[s] = *(const bf16x8*)&kT[s * 512 + ko];
#pragma unroll
        for (int t = 0; t < 4; ++t) vf[t] = *(const bf16x8*)&vT[voff[t]];
    };

    auto compute = [&](const bf16x8* kf, const bf16x8* vf) {
        // S^T[kl][ql] = sum_d K[kl][d] * Q[ql][d]
        f32x16 sT0, sT1;
#pragma unroll
        for (int ii = 0; ii < 16; ++ii) { sT0[ii] = 0.f; sT1[ii] = 0.f; }
        __builtin_amdgcn_s_setprio(1);
#pragma unroll
        for (int s = 0; s < 8; ++s) {
            sT0 = __builtin_amdgcn_mfma_f32_32x32x16_bf16(kf[s], qf0[s], sT0, 0, 0, 0);
            sT1 = __builtin_amdgcn_mfma_f32_32x32x16_bf16(kf[s], qf1[s], sT1, 0, 0, 0);
        }
        __builtin_amdgcn_s_setprio(0);

        // fixed-max softmax in-register; pack pairs -> PV B-frags
        unsigned pw0[8], pw1[8];
#pragma unroll
        for (int ii = 0; ii < 8; ++ii) {
            float a0 = fexp2(sT0[2 * ii]);
            float b0 = fexp2(sT0[2 * ii + 1]);
            float a1 = fexp2(sT1[2 * ii]);
            float b1 = fexp2(sT1[2 * ii + 1]);
            lp0 += a0 + b0;
            lp1 += a1 + b1;
            unsigned r0, r1;
            asm("v_cvt_pk_bf16_f32 %0, %1, %2" : "=v"(r0) : "v"(a0), "v"(b0));
            asm("v_cvt_pk_bf16_f32 %0, %1, %2" : "=v"(r1) : "v"(a1), "v"(b1));
            pw0[ii] = r0;
            pw1[ii] = r1;
        }
        bf16x8 p0a = __builtin_bit_cast(bf16x8, (u32x4){pw0[0], pw0[1], pw0[2], pw0[3]});
        bf16x8 p0b = __builtin_bit_cast(bf16x8, (u32x4){pw0[4], pw0[5], pw0[6], pw0[7]});
        bf16x8 p1a = __builtin_bit_cast(bf16x8, (u32x4){pw1[0], pw1[1], pw1[2], pw1[3]});
        bf16x8 p1b = __builtin_bit_cast(bf16x8, (u32x4){pw1[4], pw1[5], pw1[6], pw1[7]});

        // O[dv][ql] += V . P^T (this wave's dv-half only)
        __builtin_amdgcn_s_setprio(1);
#pragma unroll
        for (int t2 = 0; t2 < 2; ++t2) {
            acc0[t2] = __builtin_amdgcn_mfma_f32_32x32x16_bf16(vf[t2 * 2],     p0a, acc0[t2], 0, 0, 0);
            acc0[t2] = __builtin_amdgcn_mfma_f32_32x32x16_bf16(vf[t2 * 2 + 1], p0b, acc0[t2], 0, 0, 0);
            acc1[t2] = __builtin_amdgcn_mfma_f32_32x32x16_bf16(vf[t2 * 2],     p1a, acc1[t2], 0, 0, 0);
            acc1[t2] = __builtin_amdgcn_mfma_f32_32x32x16_bf16(vf[t2 * 2 + 1], p1b, acc1[t2], 0, 0, 0);
        }
        __builtin_amdgcn_s_setprio(0);
    };

    // software pipeline: loads for tile j+1 issue before compute of tile j
    load_tile(0, kfA, vfA);
    for (int kt = 0; kt < SEQ / BK; kt += 2) {
        load_tile(kt + 1, kfB, vfB);           // prefetch odd tile
        compute(kfA, vfA);
        if (kt + 2 < SEQ / BK) load_tile(kt + 2, kfA, vfA);   // prefetch next even
        compute(kfB, vfB);
    }

    // epilogue: L[ql] = lp(hi=0) + lp(hi=1) over the FULL sequence (wave-local)
    const float gm = gamma[0];
    const float L0 = lp0 + __shfl_xor(lp0, 32);
    const float L1 = lp1 + __shfl_xor(lp1, 32);
    const float sc0 = gm / L0;
    const float sc1 = gm / L1;
#pragma unroll
    for (int t2 = 0; t2 < 2; ++t2)
#pragma unroll
        for (int r = 0; r < 16; ++r) {
            int dvr = 32 * (dh * 2 + t2) + (r & 3) + 8 * (r >> 2) + 4 * hi;
            op[(size_t)dvr * SEQ + ql0 + c5]      = acc0[t2][r] * sc0;
            op[(size_t)dvr * SEQ + ql0 + 32 + c5] = acc1[t2][r] * sc1;
        }
}

extern "C" void kernel_launch(void* const* d_in, const int* in_sizes, int n_in,
                              void* d_out, int out_size, void* d_ws, size_t ws_size,
                              hipStream_t stream) {
    (void)in_sizes; (void)n_in; (void)out_size; (void)ws_size;
    const float* q = (const float*)d_in[0];
    const float* k = (const float*)d_in[1];
    const float* v = (const float*)d_in[2];
    const float* g = (const float*)d_in[3];
    float* out = (float*)d_out;

    // ws: K frags bf16 (16 MB) | V frags bf16 (16 MB)
    const size_t PER_T = (size_t)NBH * SEQ * DHEAD;
    unsigned short* kws = (unsigned short*)d_ws;
    unsigned short* vws = kws + PER_T;

    cvt_kernel<<<dim3(4096 + 4096), dim3(256), 0, stream>>>(k, v, kws, vws);
    attn_main<<<dim3(512), dim3(256), 0, stream>>>(q, kws, vws, g, out);
}